// Round 6
// baseline (392.429 us; speedup 1.0000x reference)
//
#include <hip/hip_runtime.h>

#define TD 256  // feature dim

typedef __attribute__((ext_vector_type(8))) short short8;
typedef __attribute__((ext_vector_type(8))) unsigned short ushort8;
typedef __attribute__((ext_vector_type(4))) float f32x4;

__device__ inline unsigned short f2bf(float f) {
  unsigned u = __float_as_uint(f);
  u = u + 0x7fffu + ((u >> 16) & 1u);  // round-to-nearest-even
  return (unsigned short)(u >> 16);
}
__device__ inline float bf2f(unsigned short h) {
  return __uint_as_float(((unsigned)h) << 16);
}

// ===========================================================================
// CSR build: histogram -> 3-phase parallel scan -> fill
// ===========================================================================
__global__ __launch_bounds__(256) void hist_kernel(
    const int* __restrict__ ei, int E1, const int* __restrict__ ei2, int E2,
    int* __restrict__ deg1, int* __restrict__ deg2) {
  int stride = gridDim.x * blockDim.x;
  int Emax = max(E1, E2);
  for (int i = blockIdx.x * blockDim.x + threadIdx.x; i < Emax; i += stride) {
    if (i < E1) atomicAdd(&deg1[ei[E1 + i]], 1);
    if (i < E2) atomicAdd(&deg2[ei2[E2 + i]], 1);
  }
}

// Phase A: per-block sums. grid = 512 (arr = bid>>8, b = bid&255), N<=65536.
__global__ __launch_bounds__(256) void scan_partial_kernel(
    const int* __restrict__ deg1, const int* __restrict__ deg2, int N,
    int* __restrict__ bsum) {
  int arr = blockIdx.x >> 8;
  int b = blockIdx.x & 255;
  const int* deg = arr ? deg2 : deg1;
  int i = b * 256 + threadIdx.x;
  int v = (i < N) ? deg[i] : 0;
#pragma unroll
  for (int m = 1; m < 64; m <<= 1) v += __shfl_xor(v, m, 64);
  __shared__ int wsum[4];
  if ((threadIdx.x & 63) == 0) wsum[threadIdx.x >> 6] = v;
  __syncthreads();
  if (threadIdx.x == 0)
    bsum[blockIdx.x] = wsum[0] + wsum[1] + wsum[2] + wsum[3];
}

// Phase B: one block scans both 256-segments of bsum (exclusive, in place).
__global__ __launch_bounds__(512) void scan_bsum_kernel(
    int* __restrict__ bsum, int* __restrict__ off1, int* __restrict__ off2,
    int N) {
  __shared__ int sm[512];
  int t = threadIdx.x;
  int v = bsum[t];
  sm[t] = v;
  __syncthreads();
  for (int d = 1; d < 256; d <<= 1) {
    int val = ((t & 255) >= d) ? sm[t - d] : 0;
    __syncthreads();
    sm[t] += val;
    __syncthreads();
  }
  bsum[t] = sm[t] - v;            // exclusive block offset
  if (t == 255) off1[N] = sm[t];  // total array 1
  if (t == 511) off2[N] = sm[t];  // total array 2
}

// Phase C: in-block exclusive scan + block offset -> off[], cur[].
__global__ __launch_bounds__(256) void scan_fill_kernel(
    const int* __restrict__ deg1, const int* __restrict__ deg2,
    const int* __restrict__ bsum, int N,
    int* __restrict__ off1, int* __restrict__ cur1,
    int* __restrict__ off2, int* __restrict__ cur2) {
  int arr = blockIdx.x >> 8;
  int b = blockIdx.x & 255;
  const int* deg = arr ? deg2 : deg1;
  int* off = arr ? off2 : off1;
  int* cur = arr ? cur2 : cur1;
  int i = b * 256 + threadIdx.x;
  __shared__ int sm[256];
  int v = (i < N) ? deg[i] : 0;
  sm[threadIdx.x] = v;
  __syncthreads();
  for (int d = 1; d < 256; d <<= 1) {
    int val = (threadIdx.x >= d) ? sm[threadIdx.x - d] : 0;
    __syncthreads();
    sm[threadIdx.x] += val;
    __syncthreads();
  }
  int e = sm[threadIdx.x] - v + bsum[blockIdx.x];
  if (i < N) {
    off[i] = e;
    cur[i] = e;
  }
}

__global__ __launch_bounds__(256) void fill_kernel(
    const int* __restrict__ ei, int E1, const int* __restrict__ ei2, int E2,
    int* __restrict__ cur1, int* __restrict__ cur2,
    int* __restrict__ csr1, int* __restrict__ csr2) {
  int stride = gridDim.x * blockDim.x;
  int Emax = max(E1, E2);
  for (int i = blockIdx.x * blockDim.x + threadIdx.x; i < Emax; i += stride) {
    if (i < E1) {
      int d = ei[E1 + i];
      int p = atomicAdd(&cur1[d], 1);
      csr1[p] = ei[i];
    }
    if (i < E2) {
      int d = ei2[E2 + i];
      int p = atomicAdd(&cur2[d], 1);
      csr2[p] = ei2[i];
    }
  }
}

// ===========================================================================
// Conversions
// ===========================================================================
__global__ __launch_bounds__(256) void convert_x_kernel(
    const float* __restrict__ x, unsigned short* __restrict__ xb, long total8) {
  long t = (long)blockIdx.x * blockDim.x + threadIdx.x;
  if (t >= total8) return;
  const float4 f0 = *reinterpret_cast<const float4*>(x + t * 8);
  const float4 f1 = *reinterpret_cast<const float4*>(x + t * 8 + 4);
  ushort8 o;
  o[0] = f2bf(f0.x); o[1] = f2bf(f0.y); o[2] = f2bf(f0.z); o[3] = f2bf(f0.w);
  o[4] = f2bf(f1.x); o[5] = f2bf(f1.y); o[6] = f2bf(f1.z); o[7] = f2bf(f1.w);
  *reinterpret_cast<ushort8*>(xb + t * 8) = o;
}

// Bt[m][n][k] = W_m[k][n], bf16.  One block per (matrix, n) pair.
__global__ __launch_bounds__(256) void convert_w_kernel(
    const float* __restrict__ W0, const float* __restrict__ W1,
    const float* __restrict__ Wq, const float* __restrict__ Wk,
    const float* __restrict__ Wv, unsigned short* __restrict__ wt) {
  int m = blockIdx.x >> 8;
  int n = blockIdx.x & 255;
  int k = threadIdx.x;
  const float* W = m == 0 ? W0 : m == 1 ? W1 : m == 2 ? Wq : m == 3 ? Wk : Wv;
  wt[m * 65536 + n * 256 + k] = f2bf(W[k * 256 + n]);
}

// ===========================================================================
// agg[n] = sum_{e: dst=n} x[src_e]  (bf16 in, fp32 acc, bf16 out)
// ===========================================================================
__global__ __launch_bounds__(256) void gather_x_kernel(
    const unsigned short* __restrict__ xb, const int* __restrict__ off,
    const int* __restrict__ csr, int N, unsigned short* __restrict__ aggb) {
  int wid = blockIdx.x * 4 + (threadIdx.x >> 6);
  if (wid >= N) return;
  int lane = threadIdx.x & 63;
  int beg = off[wid], end = off[wid + 1];
  float ax = 0.f, ay = 0.f, az = 0.f, aw = 0.f;
  for (int j = beg; j < end; j++) {
    int s = csr[j];
    ushort4 xv = *reinterpret_cast<const ushort4*>(xb + (size_t)s * TD + lane * 4);
    ax += bf2f(xv.x); ay += bf2f(xv.y); az += bf2f(xv.z); aw += bf2f(xv.w);
  }
  ushort4 o;
  o.x = f2bf(ax); o.y = f2bf(ay); o.z = f2bf(az); o.w = f2bf(aw);
  *reinterpret_cast<ushort4*>(aggb + (size_t)wid * TD + lane * 4) = o;
}

// ===========================================================================
// out[n] -= sum_{e: d=n} (q[n].k[s_e]) * v[s_e]   (q,k,v bf16; out fp32)
// ===========================================================================
__global__ __launch_bounds__(256) void gather_attn_kernel(
    const unsigned short* __restrict__ qb, const unsigned short* __restrict__ kb,
    const unsigned short* __restrict__ vb, const int* __restrict__ off,
    const int* __restrict__ csr, int N, float* __restrict__ out) {
  int wid = blockIdx.x * 4 + (threadIdx.x >> 6);
  if (wid >= N) return;
  int lane = threadIdx.x & 63;
  ushort4 qv = *reinterpret_cast<const ushort4*>(qb + (size_t)wid * TD + lane * 4);
  float qx = bf2f(qv.x), qy = bf2f(qv.y), qz = bf2f(qv.z), qw = bf2f(qv.w);
  float* op = out + (size_t)wid * TD + lane * 4;
  float4 acc = *reinterpret_cast<const float4*>(op);
  int beg = off[wid], end = off[wid + 1];
  for (int j = beg; j < end; j++) {
    int s = csr[j];
    ushort4 kv = *reinterpret_cast<const ushort4*>(kb + (size_t)s * TD + lane * 4);
    float p = qx * bf2f(kv.x) + qy * bf2f(kv.y) + qz * bf2f(kv.z) + qw * bf2f(kv.w);
#pragma unroll
    for (int m = 1; m < 64; m <<= 1) p += __shfl_xor(p, m, 64);
    ushort4 vv = *reinterpret_cast<const ushort4*>(vb + (size_t)s * TD + lane * 4);
    acc.x -= p * bf2f(vv.x);
    acc.y -= p * bf2f(vv.y);
    acc.z -= p * bf2f(vv.z);
    acc.w -= p * bf2f(vv.w);
  }
  *reinterpret_cast<float4*>(op) = acc;
}

// ===========================================================================
// Register-only fused MFMA GEMM: no LDS, no barriers.
// Wave-tile decomposition: global wave id t = blockIdx.x*4 + w.
//   panel = t>>4  (64 A-rows, shared by 16 consecutive waves -> L1/L2 reuse)
//   tgt   = (t>>2)&3   0:q 1:k 2:v (K=256)   3: out = x@W0 + agg@W1 (K=512)
//   cg    = t&3        64-col group within the 256 output cols
// Each wave computes a 64x64 tile: acc[4][4] of 16x16, operands loaded
// straight from global (B matrices are 640KB total -> L2 resident; A panel
// is read by 4 waves/block + 4 blocks -> L1/L2 served after first touch).
// ===========================================================================
__global__ __launch_bounds__(256) void gemm_reg(
    const unsigned short* __restrict__ xb, const unsigned short* __restrict__ aggb,
    const unsigned short* __restrict__ wt, float* __restrict__ out,
    unsigned short* __restrict__ qb, unsigned short* __restrict__ kb,
    unsigned short* __restrict__ vb, int M) {
  const int t = blockIdx.x * 4 + (threadIdx.x >> 6);
  const int l = threadIdx.x & 63;
  const int panel = t >> 4;
  const int tgt = (t >> 2) & 3;
  const int cg = t & 3;
  const int m0 = panel * 64;
  const int n0 = cg * 64;
  const int lc = l & 15;  // col lane within 16x16 tile
  const int lk = l >> 4;  // k-group (4 groups x 8 elems = K32)

  // per-lane A row indices, clamped (stores are guarded)
  int ra[4];
#pragma unroll
  for (int m = 0; m < 4; m++) {
    int r = m0 + m * 16 + lc;
    ra[m] = r < M ? r : M - 1;
  }

  f32x4 acc[4][4] = {};
  const int KTOT = (tgt == 3) ? 512 : 256;
  const unsigned short* Bqkv = wt + (tgt + 2) * 65536;

#pragma unroll 2
  for (int ks = 0; ks < KTOT; ks += 32) {
    const unsigned short* Ap;
    const unsigned short* Bp;
    int k2;
    if (tgt == 3) {
      if (ks < 256) { Ap = xb;   Bp = wt;         k2 = ks; }
      else          { Ap = aggb; Bp = wt + 65536; k2 = ks - 256; }
    } else {
      Ap = xb; Bp = Bqkv; k2 = ks;
    }
    const int ko = k2 + lk * 8;
    short8 a[4], b[4];
#pragma unroll
    for (int m = 0; m < 4; m++)
      a[m] = *reinterpret_cast<const short8*>(Ap + (size_t)ra[m] * TD + ko);
#pragma unroll
    for (int n = 0; n < 4; n++)
      b[n] = *reinterpret_cast<const short8*>(Bp + (size_t)(n0 + n * 16 + lc) * TD + ko);
#pragma unroll
    for (int m = 0; m < 4; m++)
#pragma unroll
      for (int n = 0; n < 4; n++)
        acc[m][n] =
            __builtin_amdgcn_mfma_f32_16x16x32_bf16(a[m], b[n], acc[m][n], 0, 0, 0);
  }

  // ---- store (C/D layout: col = lane&15, row = (lane>>4)*4 + j) ----
  if (tgt == 3) {
#pragma unroll
    for (int m = 0; m < 4; m++)
#pragma unroll
      for (int n = 0; n < 4; n++)
#pragma unroll
        for (int j = 0; j < 4; j++) {
          int r = m0 + m * 16 + lk * 4 + j;
          if (r < M) out[(size_t)r * TD + n0 + n * 16 + lc] = acc[m][n][j];
        }
  } else {
    unsigned short* T = tgt == 0 ? qb : tgt == 1 ? kb : vb;
#pragma unroll
    for (int m = 0; m < 4; m++)
#pragma unroll
      for (int n = 0; n < 4; n++)
#pragma unroll
        for (int j = 0; j < 4; j++) {
          int r = m0 + m * 16 + lk * 4 + j;
          if (r < M)
            T[(size_t)r * TD + n0 + n * 16 + lc] = f2bf(acc[m][n][j]);
        }
  }
}

// ===========================================================================
extern "C" void kernel_launch(void* const* d_in, const int* in_sizes, int n_in,
                              void* d_out, int out_size, void* d_ws,
                              size_t ws_size, hipStream_t stream) {
  const float* x  = (const float*)d_in[0];
  const int*   ei  = (const int*)d_in[1];
  const int*   ei2 = (const int*)d_in[2];
  const float* W0 = (const float*)d_in[3];
  const float* W1 = (const float*)d_in[4];
  const float* Wq = (const float*)d_in[5];
  const float* Wk = (const float*)d_in[6];
  const float* Wv = (const float*)d_in[7];

  const int N  = in_sizes[0] / TD;
  const int E1 = in_sizes[1] / 2;
  const int E2 = in_sizes[2] / 2;

  float* out = (float*)d_out;
  const size_t rowN = (size_t)N * TD;  // elements per [N,256] buffer

  // ---- workspace layout (bf16 buffers as ushort) ----
  char* p = (char*)d_ws;
  unsigned short* xb   = (unsigned short*)p; p += rowN * 2;
  unsigned short* aggb = (unsigned short*)p; p += rowN * 2;
  unsigned short* qb   = (unsigned short*)p; p += rowN * 2;
  unsigned short* kb   = (unsigned short*)p; p += rowN * 2;
  unsigned short* vb   = (unsigned short*)p; p += rowN * 2;
  unsigned short* wt   = (unsigned short*)p; p += 5 * 65536 * 2;
  int* off1 = (int*)p; p += (N + 1) * 4;
  int* cur1 = (int*)p; p += N * 4;
  int* off2 = (int*)p; p += (N + 1) * 4;
  int* cur2 = (int*)p; p += N * 4;
  int* csr1 = (int*)p; p += (size_t)E1 * 4;
  int* csr2 = (int*)p; p += (size_t)E2 * 4;
  int* deg1 = (int*)p; p += N * 4;
  int* deg2 = (int*)p; p += N * 4;
  int* bsum = (int*)p; p += 512 * 4;

  // 1. CSR build
  hipMemsetAsync(deg1, 0, (size_t)2 * N * sizeof(int), stream);  // deg1+deg2
  hist_kernel<<<1024, 256, 0, stream>>>(ei, E1, ei2, E2, deg1, deg2);
  scan_partial_kernel<<<512, 256, 0, stream>>>(deg1, deg2, N, bsum);
  scan_bsum_kernel<<<1, 512, 0, stream>>>(bsum, off1, off2, N);
  scan_fill_kernel<<<512, 256, 0, stream>>>(deg1, deg2, bsum, N, off1, cur1,
                                            off2, cur2);
  fill_kernel<<<1024, 256, 0, stream>>>(ei, E1, ei2, E2, cur1, cur2, csr1, csr2);

  // 2. conversions
  long total8 = rowN / 8;
  convert_x_kernel<<<(int)((total8 + 255) / 256), 256, 0, stream>>>(x, xb, total8);
  convert_w_kernel<<<5 * 256, 256, 0, stream>>>(W0, W1, Wq, Wk, Wv, wt);

  // 3. agg (bf16)
  gather_x_kernel<<<(N + 3) / 4, 256, 0, stream>>>(xb, off1, csr1, N, aggb);

  // 4. all five GEMMs in one barrier-free dispatch
  int panels = (N + 63) / 64;
  gemm_reg<<<panels * 4, 256, 0, stream>>>(xb, aggb, wt, out, qb, kb, vb, N);

  // 5. out -= gather(score * v)
  gather_attn_kernel<<<(N + 3) / 4, 256, 0, stream>>>(qb, kb, vb, off2, csr2, N, out);
}

// Round 7
// 243.432 us; speedup vs baseline: 1.6121x; 1.6121x over previous
//
#include <hip/hip_runtime.h>

#define TD 256  // feature dim

typedef __attribute__((ext_vector_type(8))) short short8;
typedef __attribute__((ext_vector_type(8))) unsigned short ushort8;
typedef __attribute__((ext_vector_type(4))) float f32x4;

__device__ inline unsigned short f2bf(float f) {
  unsigned u = __float_as_uint(f);
  u = u + 0x7fffu + ((u >> 16) & 1u);  // round-to-nearest-even
  return (unsigned short)(u >> 16);
}
__device__ inline float bf2f(unsigned short h) {
  return __uint_as_float(((unsigned)h) << 16);
}

// ===========================================================================
// CSR build: histogram -> 3-phase parallel scan -> fill
// ===========================================================================
__global__ __launch_bounds__(256) void hist_kernel(
    const int* __restrict__ ei, int E1, const int* __restrict__ ei2, int E2,
    int* __restrict__ deg1, int* __restrict__ deg2) {
  int stride = gridDim.x * blockDim.x;
  int Emax = max(E1, E2);
  for (int i = blockIdx.x * blockDim.x + threadIdx.x; i < Emax; i += stride) {
    if (i < E1) atomicAdd(&deg1[ei[E1 + i]], 1);
    if (i < E2) atomicAdd(&deg2[ei2[E2 + i]], 1);
  }
}

// Phase A: per-block sums. grid = 512 (arr = bid>>8, b = bid&255), N<=65536.
__global__ __launch_bounds__(256) void scan_partial_kernel(
    const int* __restrict__ deg1, const int* __restrict__ deg2, int N,
    int* __restrict__ bsum) {
  int arr = blockIdx.x >> 8;
  int b = blockIdx.x & 255;
  const int* deg = arr ? deg2 : deg1;
  int i = b * 256 + threadIdx.x;
  int v = (i < N) ? deg[i] : 0;
#pragma unroll
  for (int m = 1; m < 64; m <<= 1) v += __shfl_xor(v, m, 64);
  __shared__ int wsum[4];
  if ((threadIdx.x & 63) == 0) wsum[threadIdx.x >> 6] = v;
  __syncthreads();
  if (threadIdx.x == 0)
    bsum[blockIdx.x] = wsum[0] + wsum[1] + wsum[2] + wsum[3];
}

// Phase B: one block scans both 256-segments of bsum (exclusive, in place).
__global__ __launch_bounds__(512) void scan_bsum_kernel(
    int* __restrict__ bsum, int* __restrict__ off1, int* __restrict__ off2,
    int N) {
  __shared__ int sm[512];
  int t = threadIdx.x;
  int v = bsum[t];
  sm[t] = v;
  __syncthreads();
  for (int d = 1; d < 256; d <<= 1) {
    int val = ((t & 255) >= d) ? sm[t - d] : 0;
    __syncthreads();
    sm[t] += val;
    __syncthreads();
  }
  bsum[t] = sm[t] - v;            // exclusive block offset
  if (t == 255) off1[N] = sm[t];
  if (t == 511) off2[N] = sm[t];
}

// Phase C: in-block exclusive scan + block offset -> off[], cur[].
__global__ __launch_bounds__(256) void scan_fill_kernel(
    const int* __restrict__ deg1, const int* __restrict__ deg2,
    const int* __restrict__ bsum, int N,
    int* __restrict__ off1, int* __restrict__ cur1,
    int* __restrict__ off2, int* __restrict__ cur2) {
  int arr = blockIdx.x >> 8;
  int b = blockIdx.x & 255;
  const int* deg = arr ? deg2 : deg1;
  int* off = arr ? off2 : off1;
  int* cur = arr ? cur2 : cur1;
  int i = b * 256 + threadIdx.x;
  __shared__ int sm[256];
  int v = (i < N) ? deg[i] : 0;
  sm[threadIdx.x] = v;
  __syncthreads();
  for (int d = 1; d < 256; d <<= 1) {
    int val = (threadIdx.x >= d) ? sm[threadIdx.x - d] : 0;
    __syncthreads();
    sm[threadIdx.x] += val;
    __syncthreads();
  }
  int e = sm[threadIdx.x] - v + bsum[blockIdx.x];
  if (i < N) {
    off[i] = e;
    cur[i] = e;
  }
}

__global__ __launch_bounds__(256) void fill_kernel(
    const int* __restrict__ ei, int E1, const int* __restrict__ ei2, int E2,
    int* __restrict__ cur1, int* __restrict__ cur2,
    int* __restrict__ csr1, int* __restrict__ csr2) {
  int stride = gridDim.x * blockDim.x;
  int Emax = max(E1, E2);
  for (int i = blockIdx.x * blockDim.x + threadIdx.x; i < Emax; i += stride) {
    if (i < E1) {
      int d = ei[E1 + i];
      int p = atomicAdd(&cur1[d], 1);
      csr1[p] = ei[i];
    }
    if (i < E2) {
      int d = ei2[E2 + i];
      int p = atomicAdd(&cur2[d], 1);
      csr2[p] = ei2[i];
    }
  }
}

// ===========================================================================
// Conversions
// ===========================================================================
__global__ __launch_bounds__(256) void convert_x_kernel(
    const float* __restrict__ x, unsigned short* __restrict__ xb, long total8) {
  long t = (long)blockIdx.x * blockDim.x + threadIdx.x;
  if (t >= total8) return;
  const float4 f0 = *reinterpret_cast<const float4*>(x + t * 8);
  const float4 f1 = *reinterpret_cast<const float4*>(x + t * 8 + 4);
  ushort8 o;
  o[0] = f2bf(f0.x); o[1] = f2bf(f0.y); o[2] = f2bf(f0.z); o[3] = f2bf(f0.w);
  o[4] = f2bf(f1.x); o[5] = f2bf(f1.y); o[6] = f2bf(f1.z); o[7] = f2bf(f1.w);
  *reinterpret_cast<ushort8*>(xb + t * 8) = o;
}

// wt[m][n][k] = W_m[k][n], bf16, for m in {W0, W1, Wv}.
__global__ __launch_bounds__(256) void convert_wt_kernel(
    const float* __restrict__ W0, const float* __restrict__ W1,
    const float* __restrict__ Wv, unsigned short* __restrict__ wt) {
  int m = blockIdx.x >> 8;
  int n = blockIdx.x & 255;
  int k = threadIdx.x;
  const float* W = m == 0 ? W0 : m == 1 ? W1 : Wv;
  wt[m * 65536 + n * 256 + k] = f2bf(W[k * 256 + n]);
}

// row-major bf16 copies of Wq, Wk (for the G mini-GEMM)
__global__ __launch_bounds__(256) void convert_rm_kernel(
    const float* __restrict__ Wq, const float* __restrict__ Wk,
    unsigned short* __restrict__ wqb, unsigned short* __restrict__ wkb) {
  int t = blockIdx.x * blockDim.x + threadIdx.x;  // 0..16383, 8 elems each
  const float* src = (t < 8192) ? Wq : Wk;
  unsigned short* dst = (t < 8192) ? wqb : wkb;
  int o = (t & 8191) * 8;
  ushort8 r;
#pragma unroll
  for (int j = 0; j < 8; j++) r[j] = f2bf(src[o + j]);
  *reinterpret_cast<ushort8*>(dst + o) = r;
}

// ===========================================================================
// G mini-GEMM: P[a][b] = sum_f Wq[a,f] * Wk[b,f]  (256x256x256)
// stored transposed for the q' GEMM: gt[b*256 + a] = bf16(P[a][b]).
// 4 blocks x 4 waves, each wave one 64x64 tile; operands direct from global
// (matrices are 128KB each -> L1/L2-resident; tiny load count).
// ===========================================================================
__global__ __launch_bounds__(256) void gemmG_kernel(
    const unsigned short* __restrict__ wqb, const unsigned short* __restrict__ wkb,
    unsigned short* __restrict__ gt) {
  const int t = blockIdx.x * 4 + (threadIdx.x >> 6);
  const int l = threadIdx.x & 63;
  const int a0 = (t >> 2) * 64;
  const int b0 = (t & 3) * 64;
  const int lc = l & 15;
  const int lk = l >> 4;

  f32x4 acc[4][4] = {};
#pragma unroll
  for (int ks = 0; ks < 256; ks += 32) {
    const int ko = ks + lk * 8;
    short8 a[4], b[4];
#pragma unroll
    for (int m = 0; m < 4; m++)
      a[m] = *reinterpret_cast<const short8*>(wqb + (a0 + m * 16 + lc) * 256 + ko);
#pragma unroll
    for (int n = 0; n < 4; n++)
      b[n] = *reinterpret_cast<const short8*>(wkb + (b0 + n * 16 + lc) * 256 + ko);
#pragma unroll
    for (int m = 0; m < 4; m++)
#pragma unroll
      for (int n = 0; n < 4; n++)
        acc[m][n] =
            __builtin_amdgcn_mfma_f32_16x16x32_bf16(a[m], b[n], acc[m][n], 0, 0, 0);
  }
#pragma unroll
  for (int m = 0; m < 4; m++)
#pragma unroll
    for (int n = 0; n < 4; n++)
#pragma unroll
      for (int j = 0; j < 4; j++) {
        int a = a0 + m * 16 + lk * 4 + j;   // P row
        int b = b0 + n * 16 + lc;           // P col
        gt[b * 256 + a] = f2bf(acc[m][n][j]);  // transpose store
      }
}

// ===========================================================================
// Fused gather (both graphs), one wave per node:
//   aggb[n] = sum_{e in csr1(n)} x[s]            (bf16 out)
//   tb[n]   = -sum_{e in csr2(n)} (q'[n].x[s]) x[s]   (bf16 out)
// Only ONE x-row read per edge (row reused for score and accumulate).
// ===========================================================================
__global__ __launch_bounds__(256) void gather_fused_kernel(
    const unsigned short* __restrict__ xb, const unsigned short* __restrict__ qb,
    const int* __restrict__ off1, const int* __restrict__ csr1,
    const int* __restrict__ off2, const int* __restrict__ csr2,
    int N, unsigned short* __restrict__ aggb, unsigned short* __restrict__ tb) {
  int wid = blockIdx.x * 4 + (threadIdx.x >> 6);
  if (wid >= N) return;
  int lane = threadIdx.x & 63;

  // --- graph 1: agg ---
  {
    int beg = off1[wid], end = off1[wid + 1];
    float ax = 0.f, ay = 0.f, az = 0.f, aw = 0.f;
    for (int j = beg; j < end; j++) {
      int s = csr1[j];
      ushort4 xv = *reinterpret_cast<const ushort4*>(xb + (size_t)s * TD + lane * 4);
      ax += bf2f(xv.x); ay += bf2f(xv.y); az += bf2f(xv.z); aw += bf2f(xv.w);
    }
    ushort4 o;
    o.x = f2bf(ax); o.y = f2bf(ay); o.z = f2bf(az); o.w = f2bf(aw);
    *reinterpret_cast<ushort4*>(aggb + (size_t)wid * TD + lane * 4) = o;
  }

  // --- graph 2: t = -sum (q'.x[s]) x[s] ---
  {
    ushort4 qv = *reinterpret_cast<const ushort4*>(qb + (size_t)wid * TD + lane * 4);
    float qx = bf2f(qv.x), qy = bf2f(qv.y), qz = bf2f(qv.z), qw = bf2f(qv.w);
    int beg = off2[wid], end = off2[wid + 1];
    float tx = 0.f, ty = 0.f, tz = 0.f, tw = 0.f;
    for (int j = beg; j < end; j++) {
      int s = csr2[j];
      ushort4 xv = *reinterpret_cast<const ushort4*>(xb + (size_t)s * TD + lane * 4);
      float x0 = bf2f(xv.x), x1 = bf2f(xv.y), x2 = bf2f(xv.z), x3 = bf2f(xv.w);
      float p = qx * x0 + qy * x1 + qz * x2 + qw * x3;
#pragma unroll
      for (int m = 1; m < 64; m <<= 1) p += __shfl_xor(p, m, 64);
      tx -= p * x0; ty -= p * x1; tz -= p * x2; tw -= p * x3;
    }
    ushort4 o;
    o.x = f2bf(tx); o.y = f2bf(ty); o.z = f2bf(tz); o.w = f2bf(tw);
    *reinterpret_cast<ushort4*>(tb + (size_t)wid * TD + lane * 4) = o;
  }
}

// ===========================================================================
// LDS-staged MFMA GEMM (round-5 proven structure).  grid = (2, ceil(M/128)).
//   MODE 0: q' = xb @ Gt            (K=256, bf16 out -> qb)
//   MODE 1: out = xb@W0 + aggb@W1 + tb@Wv  (K=768 segmented, fp32 out)
// Tile 128x128, 4 waves (2x2 of 64x64), KSTEP=64, 16x16x32 bf16 MFMA.
// global_load_lds(16B) staging with XOR-(row&7) slot swizzle.
// ===========================================================================
template <int MODE>
__global__ __launch_bounds__(256) void gemm_lds(
    const unsigned short* __restrict__ xb, const unsigned short* __restrict__ aggb,
    const unsigned short* __restrict__ tb, const unsigned short* __restrict__ wt,
    const unsigned short* __restrict__ gt, float* __restrict__ out,
    unsigned short* __restrict__ qb, int M) {
  __shared__ __align__(16) unsigned short sA[128 * 64];
  __shared__ __align__(16) unsigned short sB[128 * 64];

  const int n0 = blockIdx.x * 128;
  const int m0 = blockIdx.y * 128;

  const int tid = threadIdx.x;
  const int w = tid >> 6, l = tid & 63;
  const int lrow = l >> 3, lslot = l & 7;
  const int wr = w >> 1, wc = w & 1;

  f32x4 acc[4][4] = {};

  const int KTOT = (MODE == 0) ? 256 : 768;

  for (int k0 = 0; k0 < KTOT; k0 += 64) {
    const unsigned short* Ap;
    const unsigned short* Bp;
    int ks;
    if (MODE == 0) {
      Ap = xb; Bp = gt; ks = k0;
    } else {
      int seg = k0 >> 8;  // 0: x@W0, 1: agg@W1, 2: t@Wv
      Ap = seg == 0 ? xb : seg == 1 ? aggb : tb;
      Bp = wt + seg * 65536;
      ks = k0 & 255;
    }

    // ---- stage A tile [128][64] ----
#pragma unroll
    for (int i = 0; i < 4; i++) {
      int row = w * 32 + i * 8 + lrow;
      int gr = m0 + row;
      if (gr >= M) gr = M - 1;
      int g = lslot ^ lrow;
      const unsigned short* src = Ap + (size_t)gr * TD + ks + g * 8;
      unsigned short* dst = sA + (w * 32 + i * 8) * 64;
      __builtin_amdgcn_global_load_lds(
          (const __attribute__((address_space(1))) void*)src,
          (__attribute__((address_space(3))) void*)dst, 16, 0, 0);
    }
    // ---- stage B tile ----
#pragma unroll
    for (int i = 0; i < 4; i++) {
      int row = w * 32 + i * 8 + lrow;
      int g = lslot ^ lrow;
      const unsigned short* src = Bp + (size_t)(n0 + row) * TD + ks + g * 8;
      unsigned short* dst = sB + (w * 32 + i * 8) * 64;
      __builtin_amdgcn_global_load_lds(
          (const __attribute__((address_space(1))) void*)src,
          (__attribute__((address_space(3))) void*)dst, 16, 0, 0);
    }
    __syncthreads();

#pragma unroll
    for (int kk = 0; kk < 2; kk++) {
      short8 a[4], b[4];
#pragma unroll
      for (int m = 0; m < 4; m++) {
        int row = wr * 64 + m * 16 + (l & 15);
        int slot = (kk * 4 + (l >> 4)) ^ (row & 7);
        a[m] = *reinterpret_cast<const short8*>(&sA[row * 64 + slot * 8]);
      }
#pragma unroll
      for (int n = 0; n < 4; n++) {
        int row = wc * 64 + n * 16 + (l & 15);
        int slot = (kk * 4 + (l >> 4)) ^ (row & 7);
        b[n] = *reinterpret_cast<const short8*>(&sB[row * 64 + slot * 8]);
      }
#pragma unroll
      for (int m = 0; m < 4; m++)
#pragma unroll
        for (int n = 0; n < 4; n++)
          acc[m][n] =
              __builtin_amdgcn_mfma_f32_16x16x32_bf16(a[m], b[n], acc[m][n], 0, 0, 0);
    }
    __syncthreads();
  }

  // ---- store ----
  if (MODE == 1) {
#pragma unroll
    for (int m = 0; m < 4; m++)
#pragma unroll
      for (int n = 0; n < 4; n++)
#pragma unroll
        for (int j = 0; j < 4; j++) {
          int r = m0 + wr * 64 + m * 16 + (l >> 4) * 4 + j;
          if (r < M)
            out[(size_t)r * TD + n0 + wc * 64 + n * 16 + (l & 15)] = acc[m][n][j];
        }
  } else {
#pragma unroll
    for (int m = 0; m < 4; m++)
#pragma unroll
      for (int n = 0; n < 4; n++)
#pragma unroll
        for (int j = 0; j < 4; j++) {
          int r = m0 + wr * 64 + m * 16 + (l >> 4) * 4 + j;
          if (r < M)
            qb[(size_t)r * TD + n0 + wc * 64 + n * 16 + (l & 15)] =
                f2bf(acc[m][n][j]);
        }
  }
}

// ===========================================================================
extern "C" void kernel_launch(void* const* d_in, const int* in_sizes, int n_in,
                              void* d_out, int out_size, void* d_ws,
                              size_t ws_size, hipStream_t stream) {
  const float* x  = (const float*)d_in[0];
  const int*   ei  = (const int*)d_in[1];
  const int*   ei2 = (const int*)d_in[2];
  const float* W0 = (const float*)d_in[3];
  const float* W1 = (const float*)d_in[4];
  const float* Wq = (const float*)d_in[5];
  const float* Wk = (const float*)d_in[6];
  const float* Wv = (const float*)d_in[7];

  const int N  = in_sizes[0] / TD;
  const int E1 = in_sizes[1] / 2;
  const int E2 = in_sizes[2] / 2;

  float* out = (float*)d_out;
  const size_t rowN = (size_t)N * TD;

  // ---- workspace layout ----
  char* p = (char*)d_ws;
  unsigned short* xb   = (unsigned short*)p; p += rowN * 2;
  unsigned short* aggb = (unsigned short*)p; p += rowN * 2;
  unsigned short* qb   = (unsigned short*)p; p += rowN * 2;
  unsigned short* tb   = (unsigned short*)p; p += rowN * 2;
  unsigned short* wt   = (unsigned short*)p; p += 3 * 65536 * 2;  // W0t,W1t,Wvt
  unsigned short* gt   = (unsigned short*)p; p += 65536 * 2;
  unsigned short* wqb  = (unsigned short*)p; p += 65536 * 2;
  unsigned short* wkb  = (unsigned short*)p; p += 65536 * 2;
  int* off1 = (int*)p; p += (N + 1) * 4;
  int* cur1 = (int*)p; p += N * 4;
  int* off2 = (int*)p; p += (N + 1) * 4;
  int* cur2 = (int*)p; p += N * 4;
  int* csr1 = (int*)p; p += (size_t)E1 * 4;
  int* csr2 = (int*)p; p += (size_t)E2 * 4;
  int* deg1 = (int*)p; p += N * 4;
  int* deg2 = (int*)p; p += N * 4;
  int* bsum = (int*)p; p += 512 * 4;

  // 1. CSR build (both graphs)
  hipMemsetAsync(deg1, 0, (size_t)2 * N * sizeof(int), stream);
  hist_kernel<<<1024, 256, 0, stream>>>(ei, E1, ei2, E2, deg1, deg2);
  scan_partial_kernel<<<512, 256, 0, stream>>>(deg1, deg2, N, bsum);
  scan_bsum_kernel<<<1, 512, 0, stream>>>(bsum, off1, off2, N);
  scan_fill_kernel<<<512, 256, 0, stream>>>(deg1, deg2, bsum, N, off1, cur1,
                                            off2, cur2);
  fill_kernel<<<1024, 256, 0, stream>>>(ei, E1, ei2, E2, cur1, cur2, csr1, csr2);

  // 2. conversions
  long total8 = rowN / 8;
  convert_x_kernel<<<(int)((total8 + 255) / 256), 256, 0, stream>>>(x, xb, total8);
  convert_rm_kernel<<<64, 256, 0, stream>>>(Wq, Wk, wqb, wkb);
  convert_wt_kernel<<<3 * 256, 256, 0, stream>>>(W0, W1, Wv, wt);

  // 3. G = Wq @ Wk^T (transposed-store for the q' GEMM)
  gemmG_kernel<<<4, 256, 0, stream>>>(wqb, wkb, gt);

  // 4. q' = x @ G
  dim3 grid(2, (N + 127) / 128);
  gemm_lds<0><<<grid, 256, 0, stream>>>(xb, aggb, tb, wt, gt, out, qb, N);

  // 5. fused gather: aggb (graph1) + tb (graph2, needs q')
  gather_fused_kernel<<<(N + 3) / 4, 256, 0, stream>>>(xb, qb, off1, csr1,
                                                       off2, csr2, N, aggb, tb);

  // 6. out = x@W0 + agg@W1 + t@Wv   (t already negated)
  gemm_lds<1><<<grid, 256, 0, stream>>>(xb, aggb, tb, wt, gt, out, qb, N);
}

// Round 8
// 185.436 us; speedup vs baseline: 2.1163x; 1.3128x over previous
//
#include <hip/hip_runtime.h>

#define TD 256  // feature dim

typedef __attribute__((ext_vector_type(8))) short short8;
typedef __attribute__((ext_vector_type(8))) unsigned short ushort8;
typedef __attribute__((ext_vector_type(4))) float f32x4;

__device__ inline unsigned short f2bf(float f) {
  unsigned u = __float_as_uint(f);
  u = u + 0x7fffu + ((u >> 16) & 1u);  // round-to-nearest-even
  return (unsigned short)(u >> 16);
}
__device__ inline float bf2f(unsigned short h) {
  return __uint_as_float(((unsigned)h) << 16);
}

// ===========================================================================
// Prologue mega-kernel: blocks partitioned into
//   [0, nbH)               : histogram of both edge lists (atomics)
//   [nbH, nbH+nbX)         : x -> bf16
//   [.., +64)              : Wq,Wk -> bf16 row-major
//   [.., +768)             : W0,W1,Wv -> bf16 transposed (wt)
// ===========================================================================
__global__ __launch_bounds__(256) void prologue_kernel(
    const int* __restrict__ ei, int E1, const int* __restrict__ ei2, int E2,
    int* __restrict__ deg1, int* __restrict__ deg2,
    const float* __restrict__ x, unsigned short* __restrict__ xb, long total8,
    const float* __restrict__ Wq, const float* __restrict__ Wk,
    unsigned short* __restrict__ wqb, unsigned short* __restrict__ wkb,
    const float* __restrict__ W0, const float* __restrict__ W1,
    const float* __restrict__ Wv, unsigned short* __restrict__ wt,
    int nbH, int nbX) {
  int b = blockIdx.x;
  if (b < nbH) {
    int stride = nbH * 256;
    int Emax = max(E1, E2);
    for (int i = b * 256 + threadIdx.x; i < Emax; i += stride) {
      if (i < E1) atomicAdd(&deg1[ei[E1 + i]], 1);
      if (i < E2) atomicAdd(&deg2[ei2[E2 + i]], 1);
    }
  } else if (b < nbH + nbX) {
    long t = (long)(b - nbH) * 256 + threadIdx.x;
    if (t >= total8) return;
    const float4 f0 = *reinterpret_cast<const float4*>(x + t * 8);
    const float4 f1 = *reinterpret_cast<const float4*>(x + t * 8 + 4);
    ushort8 o;
    o[0] = f2bf(f0.x); o[1] = f2bf(f0.y); o[2] = f2bf(f0.z); o[3] = f2bf(f0.w);
    o[4] = f2bf(f1.x); o[5] = f2bf(f1.y); o[6] = f2bf(f1.z); o[7] = f2bf(f1.w);
    *reinterpret_cast<ushort8*>(xb + t * 8) = o;
  } else if (b < nbH + nbX + 64) {
    int t = (b - nbH - nbX) * 256 + threadIdx.x;  // 0..16383
    const float* src = (t < 8192) ? Wq : Wk;
    unsigned short* dst = (t < 8192) ? wqb : wkb;
    int o = (t & 8191) * 8;
    ushort8 r;
#pragma unroll
    for (int j = 0; j < 8; j++) r[j] = f2bf(src[o + j]);
    *reinterpret_cast<ushort8*>(dst + o) = r;
  } else {
    int b2 = b - nbH - nbX - 64;  // 0..767
    int m = b2 >> 8;
    int n = b2 & 255;
    int k = threadIdx.x;
    const float* W = m == 0 ? W0 : m == 1 ? W1 : Wv;
    wt[m * 65536 + n * 256 + k] = f2bf(W[k * 256 + n]);
  }
}

// ===========================================================================
// scan phase A (blocks 0..511) + gemmG (blocks 512..515)
//   scan A: per-block sums of deg arrays
//   gemmG: P = Wq @ Wk^T, stored transposed gt[b*256+a]
// ===========================================================================
__global__ __launch_bounds__(256) void scanA_gemmG_kernel(
    const int* __restrict__ deg1, const int* __restrict__ deg2, int N,
    int* __restrict__ bsum,
    const unsigned short* __restrict__ wqb, const unsigned short* __restrict__ wkb,
    unsigned short* __restrict__ gt) {
  if (blockIdx.x < 512) {
    int arr = blockIdx.x >> 8;
    int b = blockIdx.x & 255;
    const int* deg = arr ? deg2 : deg1;
    int i = b * 256 + threadIdx.x;
    int v = (i < N) ? deg[i] : 0;
#pragma unroll
    for (int m = 1; m < 64; m <<= 1) v += __shfl_xor(v, m, 64);
    __shared__ int wsum[4];
    if ((threadIdx.x & 63) == 0) wsum[threadIdx.x >> 6] = v;
    __syncthreads();
    if (threadIdx.x == 0)
      bsum[blockIdx.x] = wsum[0] + wsum[1] + wsum[2] + wsum[3];
    return;
  }
  // ---- gemmG: 4 blocks x 4 waves, each wave one 64x64 tile ----
  const int t = (blockIdx.x - 512) * 4 + (threadIdx.x >> 6);
  const int l = threadIdx.x & 63;
  const int a0 = (t >> 2) * 64;
  const int b0 = (t & 3) * 64;
  const int lc = l & 15;
  const int lk = l >> 4;
  f32x4 acc[4][4] = {};
#pragma unroll
  for (int ks = 0; ks < 256; ks += 32) {
    const int ko = ks + lk * 8;
    short8 a[4], b[4];
#pragma unroll
    for (int m = 0; m < 4; m++)
      a[m] = *reinterpret_cast<const short8*>(wqb + (a0 + m * 16 + lc) * 256 + ko);
#pragma unroll
    for (int n = 0; n < 4; n++)
      b[n] = *reinterpret_cast<const short8*>(wkb + (b0 + n * 16 + lc) * 256 + ko);
#pragma unroll
    for (int m = 0; m < 4; m++)
#pragma unroll
      for (int n = 0; n < 4; n++)
        acc[m][n] =
            __builtin_amdgcn_mfma_f32_16x16x32_bf16(a[m], b[n], acc[m][n], 0, 0, 0);
  }
#pragma unroll
  for (int m = 0; m < 4; m++)
#pragma unroll
    for (int n = 0; n < 4; n++)
#pragma unroll
      for (int j = 0; j < 4; j++) {
        int a = a0 + m * 16 + lk * 4 + j;
        int b = b0 + n * 16 + lc;
        gt[b * 256 + a] = f2bf(acc[m][n][j]);
      }
}

// Phase B: one block scans both 256-segments of bsum (exclusive, in place).
__global__ __launch_bounds__(512) void scan_bsum_kernel(
    int* __restrict__ bsum, int* __restrict__ off1, int* __restrict__ off2,
    int N) {
  __shared__ int sm[512];
  int t = threadIdx.x;
  int v = bsum[t];
  sm[t] = v;
  __syncthreads();
  for (int d = 1; d < 256; d <<= 1) {
    int val = ((t & 255) >= d) ? sm[t - d] : 0;
    __syncthreads();
    sm[t] += val;
    __syncthreads();
  }
  bsum[t] = sm[t] - v;
  if (t == 255) off1[N] = sm[t];
  if (t == 511) off2[N] = sm[t];
}

// Phase C: in-block exclusive scan + block offset -> off[], cur[].
__global__ __launch_bounds__(256) void scan_fill_kernel(
    const int* __restrict__ deg1, const int* __restrict__ deg2,
    const int* __restrict__ bsum, int N,
    int* __restrict__ off1, int* __restrict__ cur1,
    int* __restrict__ off2, int* __restrict__ cur2) {
  int arr = blockIdx.x >> 8;
  int b = blockIdx.x & 255;
  const int* deg = arr ? deg2 : deg1;
  int* off = arr ? off2 : off1;
  int* cur = arr ? cur2 : cur1;
  int i = b * 256 + threadIdx.x;
  __shared__ int sm[256];
  int v = (i < N) ? deg[i] : 0;
  sm[threadIdx.x] = v;
  __syncthreads();
  for (int d = 1; d < 256; d <<= 1) {
    int val = (threadIdx.x >= d) ? sm[threadIdx.x - d] : 0;
    __syncthreads();
    sm[threadIdx.x] += val;
    __syncthreads();
  }
  int e = sm[threadIdx.x] - v + bsum[blockIdx.x];
  if (i < N) {
    off[i] = e;
    cur[i] = e;
  }
}

__global__ __launch_bounds__(256) void fill_kernel(
    const int* __restrict__ ei, int E1, const int* __restrict__ ei2, int E2,
    int* __restrict__ cur1, int* __restrict__ cur2,
    int* __restrict__ csr1, int* __restrict__ csr2) {
  int stride = gridDim.x * blockDim.x;
  int Emax = max(E1, E2);
  for (int i = blockIdx.x * blockDim.x + threadIdx.x; i < Emax; i += stride) {
    if (i < E1) {
      int d = ei[E1 + i];
      int p = atomicAdd(&cur1[d], 1);
      csr1[p] = ei[i];
    }
    if (i < E2) {
      int d = ei2[E2 + i];
      int p = atomicAdd(&cur2[d], 1);
      csr2[p] = ei2[i];
    }
  }
}

// ===========================================================================
// Fused gather, 4x unrolled for memory-level parallelism.
//   aggb[n] = sum_{csr1(n)} x[s]
//   tb[n]   = -sum_{csr2(n)} (q'[n].x[s]) x[s]
// ===========================================================================
__global__ __launch_bounds__(256) void gather_fused_kernel(
    const unsigned short* __restrict__ xb, const unsigned short* __restrict__ qb,
    const int* __restrict__ off1, const int* __restrict__ csr1,
    const int* __restrict__ off2, const int* __restrict__ csr2,
    int N, unsigned short* __restrict__ aggb, unsigned short* __restrict__ tb) {
  int wid = blockIdx.x * 4 + (threadIdx.x >> 6);
  if (wid >= N) return;
  int lane = threadIdx.x & 63;

  // --- graph 1: agg (unroll 4) ---
  {
    int beg = off1[wid], end = off1[wid + 1];
    float ax = 0.f, ay = 0.f, az = 0.f, aw = 0.f;
    int j = beg;
    for (; j + 4 <= end; j += 4) {
      int s0 = csr1[j], s1 = csr1[j + 1], s2 = csr1[j + 2], s3 = csr1[j + 3];
      ushort4 r0 = *reinterpret_cast<const ushort4*>(xb + (size_t)s0 * TD + lane * 4);
      ushort4 r1 = *reinterpret_cast<const ushort4*>(xb + (size_t)s1 * TD + lane * 4);
      ushort4 r2 = *reinterpret_cast<const ushort4*>(xb + (size_t)s2 * TD + lane * 4);
      ushort4 r3 = *reinterpret_cast<const ushort4*>(xb + (size_t)s3 * TD + lane * 4);
      ax += bf2f(r0.x) + bf2f(r1.x) + bf2f(r2.x) + bf2f(r3.x);
      ay += bf2f(r0.y) + bf2f(r1.y) + bf2f(r2.y) + bf2f(r3.y);
      az += bf2f(r0.z) + bf2f(r1.z) + bf2f(r2.z) + bf2f(r3.z);
      aw += bf2f(r0.w) + bf2f(r1.w) + bf2f(r2.w) + bf2f(r3.w);
    }
    for (; j < end; j++) {
      int s = csr1[j];
      ushort4 r = *reinterpret_cast<const ushort4*>(xb + (size_t)s * TD + lane * 4);
      ax += bf2f(r.x); ay += bf2f(r.y); az += bf2f(r.z); aw += bf2f(r.w);
    }
    ushort4 o;
    o.x = f2bf(ax); o.y = f2bf(ay); o.z = f2bf(az); o.w = f2bf(aw);
    *reinterpret_cast<ushort4*>(aggb + (size_t)wid * TD + lane * 4) = o;
  }

  // --- graph 2: t = -sum (q'.x[s]) x[s]  (unroll 4, interleaved reduces) ---
  {
    ushort4 qv = *reinterpret_cast<const ushort4*>(qb + (size_t)wid * TD + lane * 4);
    float qx = bf2f(qv.x), qy = bf2f(qv.y), qz = bf2f(qv.z), qw = bf2f(qv.w);
    int beg = off2[wid], end = off2[wid + 1];
    float tx = 0.f, ty = 0.f, tz = 0.f, tw = 0.f;
    int j = beg;
    for (; j + 4 <= end; j += 4) {
      int s0 = csr2[j], s1 = csr2[j + 1], s2 = csr2[j + 2], s3 = csr2[j + 3];
      ushort4 r0 = *reinterpret_cast<const ushort4*>(xb + (size_t)s0 * TD + lane * 4);
      ushort4 r1 = *reinterpret_cast<const ushort4*>(xb + (size_t)s1 * TD + lane * 4);
      ushort4 r2 = *reinterpret_cast<const ushort4*>(xb + (size_t)s2 * TD + lane * 4);
      ushort4 r3 = *reinterpret_cast<const ushort4*>(xb + (size_t)s3 * TD + lane * 4);
      float a0x = bf2f(r0.x), a0y = bf2f(r0.y), a0z = bf2f(r0.z), a0w = bf2f(r0.w);
      float a1x = bf2f(r1.x), a1y = bf2f(r1.y), a1z = bf2f(r1.z), a1w = bf2f(r1.w);
      float a2x = bf2f(r2.x), a2y = bf2f(r2.y), a2z = bf2f(r2.z), a2w = bf2f(r2.w);
      float a3x = bf2f(r3.x), a3y = bf2f(r3.y), a3z = bf2f(r3.z), a3w = bf2f(r3.w);
      float p0 = qx * a0x + qy * a0y + qz * a0z + qw * a0w;
      float p1 = qx * a1x + qy * a1y + qz * a1z + qw * a1w;
      float p2 = qx * a2x + qy * a2y + qz * a2z + qw * a2w;
      float p3 = qx * a3x + qy * a3y + qz * a3z + qw * a3w;
#pragma unroll
      for (int m = 1; m < 64; m <<= 1) {
        p0 += __shfl_xor(p0, m, 64);
        p1 += __shfl_xor(p1, m, 64);
        p2 += __shfl_xor(p2, m, 64);
        p3 += __shfl_xor(p3, m, 64);
      }
      tx -= p0 * a0x + p1 * a1x + p2 * a2x + p3 * a3x;
      ty -= p0 * a0y + p1 * a1y + p2 * a2y + p3 * a3y;
      tz -= p0 * a0z + p1 * a1z + p2 * a2z + p3 * a3z;
      tw -= p0 * a0w + p1 * a1w + p2 * a2w + p3 * a3w;
    }
    for (; j < end; j++) {
      int s = csr2[j];
      ushort4 r = *reinterpret_cast<const ushort4*>(xb + (size_t)s * TD + lane * 4);
      float x0 = bf2f(r.x), x1 = bf2f(r.y), x2 = bf2f(r.z), x3 = bf2f(r.w);
      float p = qx * x0 + qy * x1 + qz * x2 + qw * x3;
#pragma unroll
      for (int m = 1; m < 64; m <<= 1) p += __shfl_xor(p, m, 64);
      tx -= p * x0; ty -= p * x1; tz -= p * x2; tw -= p * x3;
    }
    ushort4 o;
    o.x = f2bf(tx); o.y = f2bf(ty); o.z = f2bf(tz); o.w = f2bf(tw);
    *reinterpret_cast<ushort4*>(tb + (size_t)wid * TD + lane * 4) = o;
  }
}

// ===========================================================================
// LDS-staged MFMA GEMM, tile 128x256 (full output width), 512 thr = 8 waves
// (2 row x 4 col of 64x64).  grid = ceil(M/128).
//   MODE 0: q' = xb @ Gt                    (K=256, bf16 out -> qb)
//   MODE 1: out = xb@W0 + aggb@W1 + tb@Wv   (K=768 segmented, fp32 out)
// KSTEP=64, 16x16x32 bf16 MFMA, global_load_lds(16B) + XOR-(row&7) swizzle.
// ===========================================================================
template <int MODE>
__global__ __launch_bounds__(512) void gemm_lds(
    const unsigned short* __restrict__ xb, const unsigned short* __restrict__ aggb,
    const unsigned short* __restrict__ tb, const unsigned short* __restrict__ wt,
    const unsigned short* __restrict__ gt, float* __restrict__ out,
    unsigned short* __restrict__ qb, int M) {
  __shared__ __align__(16) unsigned short sA[128 * 64];
  __shared__ __align__(16) unsigned short sB[256 * 64];

  const int m0 = blockIdx.x * 128;
  const int tid = threadIdx.x;
  const int w = tid >> 6, l = tid & 63;
  const int lrow = l >> 3, lslot = l & 7;
  const int wr = w >> 2, wc = w & 3;  // 2x4 wave grid, 64x64 each

  f32x4 acc[4][4] = {};

  const int KTOT = (MODE == 0) ? 256 : 768;

  for (int k0 = 0; k0 < KTOT; k0 += 64) {
    const unsigned short* Ap;
    const unsigned short* Bp;
    int ks;
    if (MODE == 0) {
      Ap = xb; Bp = gt; ks = k0;
    } else {
      int seg = k0 >> 8;  // 0: x@W0, 1: agg@W1, 2: t@Wv
      Ap = seg == 0 ? xb : seg == 1 ? aggb : tb;
      Bp = wt + seg * 65536;
      ks = k0 & 255;
    }

    // ---- stage A tile [128][64]: wave w stages rows w*16 .. w*16+15 ----
#pragma unroll
    for (int i = 0; i < 2; i++) {
      int row = w * 16 + i * 8 + lrow;
      int gr = m0 + row;
      if (gr >= M) gr = M - 1;
      int g = lslot ^ lrow;
      const unsigned short* src = Ap + (size_t)gr * TD + ks + g * 8;
      unsigned short* dst = sA + (w * 16 + i * 8) * 64;
      __builtin_amdgcn_global_load_lds(
          (const __attribute__((address_space(1))) void*)src,
          (__attribute__((address_space(3))) void*)dst, 16, 0, 0);
    }
    // ---- stage B tile [256][64]: wave w stages rows w*32 .. w*32+31 ----
#pragma unroll
    for (int i = 0; i < 4; i++) {
      int row = w * 32 + i * 8 + lrow;
      int g = lslot ^ lrow;
      const unsigned short* src = Bp + (size_t)row * TD + ks + g * 8;
      unsigned short* dst = sB + (w * 32 + i * 8) * 64;
      __builtin_amdgcn_global_load_lds(
          (const __attribute__((address_space(1))) void*)src,
          (__attribute__((address_space(3))) void*)dst, 16, 0, 0);
    }
    __syncthreads();

#pragma unroll
    for (int kk = 0; kk < 2; kk++) {
      short8 a[4], b[4];
#pragma unroll
      for (int m = 0; m < 4; m++) {
        int row = wr * 64 + m * 16 + (l & 15);
        int slot = (kk * 4 + (l >> 4)) ^ (row & 7);
        a[m] = *reinterpret_cast<const short8*>(&sA[row * 64 + slot * 8]);
      }
#pragma unroll
      for (int n = 0; n < 4; n++) {
        int row = wc * 64 + n * 16 + (l & 15);
        int slot = (kk * 4 + (l >> 4)) ^ (row & 7);
        b[n] = *reinterpret_cast<const short8*>(&sB[row * 64 + slot * 8]);
      }
#pragma unroll
      for (int m = 0; m < 4; m++)
#pragma unroll
        for (int n = 0; n < 4; n++)
          acc[m][n] =
              __builtin_amdgcn_mfma_f32_16x16x32_bf16(a[m], b[n], acc[m][n], 0, 0, 0);
    }
    __syncthreads();
  }

  // ---- store: row = m0 + wr*64 + m*16 + (l>>4)*4 + j, col = wc*64 + n*16 + (l&15)
  if (MODE == 1) {
#pragma unroll
    for (int m = 0; m < 4; m++)
#pragma unroll
      for (int n = 0; n < 4; n++)
#pragma unroll
        for (int j = 0; j < 4; j++) {
          int r = m0 + wr * 64 + m * 16 + (l >> 4) * 4 + j;
          if (r < M)
            out[(size_t)r * TD + wc * 64 + n * 16 + (l & 15)] = acc[m][n][j];
        }
  } else {
#pragma unroll
    for (int m = 0; m < 4; m++)
#pragma unroll
      for (int n = 0; n < 4; n++)
#pragma unroll
        for (int j = 0; j < 4; j++) {
          int r = m0 + wr * 64 + m * 16 + (l >> 4) * 4 + j;
          if (r < M)
            qb[(size_t)r * TD + wc * 64 + n * 16 + (l & 15)] =
                f2bf(acc[m][n][j]);
        }
  }
}

// ===========================================================================
extern "C" void kernel_launch(void* const* d_in, const int* in_sizes, int n_in,
                              void* d_out, int out_size, void* d_ws,
                              size_t ws_size, hipStream_t stream) {
  const float* x  = (const float*)d_in[0];
  const int*   ei  = (const int*)d_in[1];
  const int*   ei2 = (const int*)d_in[2];
  const float* W0 = (const float*)d_in[3];
  const float* W1 = (const float*)d_in[4];
  const float* Wq = (const float*)d_in[5];
  const float* Wk = (const float*)d_in[6];
  const float* Wv = (const float*)d_in[7];

  const int N  = in_sizes[0] / TD;
  const int E1 = in_sizes[1] / 2;
  const int E2 = in_sizes[2] / 2;

  float* out = (float*)d_out;
  const size_t rowN = (size_t)N * TD;

  // ---- workspace layout ----
  char* p = (char*)d_ws;
  unsigned short* xb   = (unsigned short*)p; p += rowN * 2;
  unsigned short* aggb = (unsigned short*)p; p += rowN * 2;
  unsigned short* qb   = (unsigned short*)p; p += rowN * 2;
  unsigned short* tb   = (unsigned short*)p; p += rowN * 2;
  unsigned short* wt   = (unsigned short*)p; p += 3 * 65536 * 2;  // W0t,W1t,Wvt
  unsigned short* gt   = (unsigned short*)p; p += 65536 * 2;
  unsigned short* wqb  = (unsigned short*)p; p += 65536 * 2;
  unsigned short* wkb  = (unsigned short*)p; p += 65536 * 2;
  int* off1 = (int*)p; p += (N + 1) * 4;
  int* cur1 = (int*)p; p += N * 4;
  int* off2 = (int*)p; p += (N + 1) * 4;
  int* cur2 = (int*)p; p += N * 4;
  int* csr1 = (int*)p; p += (size_t)E1 * 4;
  int* csr2 = (int*)p; p += (size_t)E2 * 4;
  int* deg1 = (int*)p; p += N * 4;
  int* deg2 = (int*)p; p += N * 4;
  int* bsum = (int*)p; p += 512 * 4;

  // 1. zero degree arrays
  hipMemsetAsync(deg1, 0, (size_t)2 * N * sizeof(int), stream);

  // 2. prologue: hist + all dtype conversions in one dispatch
  long total8 = rowN / 8;
  int nbH = 512;
  int nbX = (int)((total8 + 255) / 256);
  prologue_kernel<<<nbH + nbX + 64 + 768, 256, 0, stream>>>(
      ei, E1, ei2, E2, deg1, deg2, x, xb, total8, Wq, Wk, wqb, wkb, W0, W1, Wv,
      wt, nbH, nbX);

  // 3. scan phase A + G = Wq@Wk^T
  scanA_gemmG_kernel<<<516, 256, 0, stream>>>(deg1, deg2, N, bsum, wqb, wkb, gt);
  scan_bsum_kernel<<<1, 512, 0, stream>>>(bsum, off1, off2, N);
  scan_fill_kernel<<<512, 256, 0, stream>>>(deg1, deg2, bsum, N, off1, cur1,
                                            off2, cur2);
  fill_kernel<<<1024, 256, 0, stream>>>(ei, E1, ei2, E2, cur1, cur2, csr1, csr2);

  // 4. q' = x @ G
  int gblk = (N + 127) / 128;
  gemm_lds<0><<<gblk, 512, 0, stream>>>(xb, aggb, tb, wt, gt, out, qb, N);

  // 5. fused gather: aggb (graph1) + tb (graph2, needs q')
  gather_fused_kernel<<<(N + 3) / 4, 256, 0, stream>>>(xb, qb, off1, csr1,
                                                       off2, csr2, N, aggb, tb);

  // 6. out = x@W0 + agg@W1 + t@Wv   (t already negated)
  gemm_lds<1><<<gblk, 512, 0, stream>>>(xb, aggb, tb, wt, gt, out, qb, N);
}

// Round 9
// 183.016 us; speedup vs baseline: 2.1442x; 1.0132x over previous
//
#include <hip/hip_runtime.h>

#define TD 256  // feature dim

typedef __attribute__((ext_vector_type(8))) short short8;
typedef __attribute__((ext_vector_type(8))) unsigned short ushort8;
typedef __attribute__((ext_vector_type(4))) float f32x4;

__device__ inline unsigned short f2bf(float f) {
  unsigned u = __float_as_uint(f);
  u = u + 0x7fffu + ((u >> 16) & 1u);  // round-to-nearest-even
  return (unsigned short)(u >> 16);
}
__device__ inline float bf2f(unsigned short h) {
  return __uint_as_float(((unsigned)h) << 16);
}

// ===========================================================================
// Prologue mega-kernel: blocks partitioned into
//   [0, nbH)               : histogram of both edge lists (atomics)
//   [nbH, nbH+nbX)         : x -> bf16
//   [.., +64)              : Wq,Wk -> bf16 row-major
//   [.., +768)             : W0,W1,Wv -> bf16 transposed (wt)
// ===========================================================================
__global__ __launch_bounds__(256) void prologue_kernel(
    const int* __restrict__ ei, int E1, const int* __restrict__ ei2, int E2,
    int* __restrict__ deg1, int* __restrict__ deg2,
    const float* __restrict__ x, unsigned short* __restrict__ xb, long total8,
    const float* __restrict__ Wq, const float* __restrict__ Wk,
    unsigned short* __restrict__ wqb, unsigned short* __restrict__ wkb,
    const float* __restrict__ W0, const float* __restrict__ W1,
    const float* __restrict__ Wv, unsigned short* __restrict__ wt,
    int nbH, int nbX) {
  int b = blockIdx.x;
  if (b < nbH) {
    int stride = nbH * 256;
    int Emax = max(E1, E2);
    for (int i = b * 256 + threadIdx.x; i < Emax; i += stride) {
      if (i < E1) atomicAdd(&deg1[ei[E1 + i]], 1);
      if (i < E2) atomicAdd(&deg2[ei2[E2 + i]], 1);
    }
  } else if (b < nbH + nbX) {
    long t = (long)(b - nbH) * 256 + threadIdx.x;
    if (t >= total8) return;
    const float4 f0 = *reinterpret_cast<const float4*>(x + t * 8);
    const float4 f1 = *reinterpret_cast<const float4*>(x + t * 8 + 4);
    ushort8 o;
    o[0] = f2bf(f0.x); o[1] = f2bf(f0.y); o[2] = f2bf(f0.z); o[3] = f2bf(f0.w);
    o[4] = f2bf(f1.x); o[5] = f2bf(f1.y); o[6] = f2bf(f1.z); o[7] = f2bf(f1.w);
    *reinterpret_cast<ushort8*>(xb + t * 8) = o;
  } else if (b < nbH + nbX + 64) {
    int t = (b - nbH - nbX) * 256 + threadIdx.x;  // 0..16383
    const float* src = (t < 8192) ? Wq : Wk;
    unsigned short* dst = (t < 8192) ? wqb : wkb;
    int o = (t & 8191) * 8;
    ushort8 r;
#pragma unroll
    for (int j = 0; j < 8; j++) r[j] = f2bf(src[o + j]);
    *reinterpret_cast<ushort8*>(dst + o) = r;
  } else {
    int b2 = b - nbH - nbX - 64;  // 0..767
    int m = b2 >> 8;
    int n = b2 & 255;
    int k = threadIdx.x;
    const float* W = m == 0 ? W0 : m == 1 ? W1 : Wv;
    wt[m * 65536 + n * 256 + k] = f2bf(W[k * 256 + n]);
  }
}

// ===========================================================================
// scan phase A (blocks 0..511) + gemmG (blocks 512..515)
// ===========================================================================
__global__ __launch_bounds__(256) void scanA_gemmG_kernel(
    const int* __restrict__ deg1, const int* __restrict__ deg2, int N,
    int* __restrict__ bsum,
    const unsigned short* __restrict__ wqb, const unsigned short* __restrict__ wkb,
    unsigned short* __restrict__ gt) {
  if (blockIdx.x < 512) {
    int arr = blockIdx.x >> 8;
    int b = blockIdx.x & 255;
    const int* deg = arr ? deg2 : deg1;
    int i = b * 256 + threadIdx.x;
    int v = (i < N) ? deg[i] : 0;
#pragma unroll
    for (int m = 1; m < 64; m <<= 1) v += __shfl_xor(v, m, 64);
    __shared__ int wsum[4];
    if ((threadIdx.x & 63) == 0) wsum[threadIdx.x >> 6] = v;
    __syncthreads();
    if (threadIdx.x == 0)
      bsum[blockIdx.x] = wsum[0] + wsum[1] + wsum[2] + wsum[3];
    return;
  }
  // ---- gemmG: 4 blocks x 4 waves, each wave one 64x64 tile ----
  const int t = (blockIdx.x - 512) * 4 + (threadIdx.x >> 6);
  const int l = threadIdx.x & 63;
  const int a0 = (t >> 2) * 64;
  const int b0 = (t & 3) * 64;
  const int lc = l & 15;
  const int lk = l >> 4;
  f32x4 acc[4][4] = {};
#pragma unroll
  for (int ks = 0; ks < 256; ks += 32) {
    const int ko = ks + lk * 8;
    short8 a[4], b[4];
#pragma unroll
    for (int m = 0; m < 4; m++)
      a[m] = *reinterpret_cast<const short8*>(wqb + (a0 + m * 16 + lc) * 256 + ko);
#pragma unroll
    for (int n = 0; n < 4; n++)
      b[n] = *reinterpret_cast<const short8*>(wkb + (b0 + n * 16 + lc) * 256 + ko);
#pragma unroll
    for (int m = 0; m < 4; m++)
#pragma unroll
      for (int n = 0; n < 4; n++)
        acc[m][n] =
            __builtin_amdgcn_mfma_f32_16x16x32_bf16(a[m], b[n], acc[m][n], 0, 0, 0);
  }
#pragma unroll
  for (int m = 0; m < 4; m++)
#pragma unroll
    for (int n = 0; n < 4; n++)
#pragma unroll
      for (int j = 0; j < 4; j++) {
        int a = a0 + m * 16 + lk * 4 + j;
        int b = b0 + n * 16 + lc;
        gt[b * 256 + a] = f2bf(acc[m][n][j]);
      }
}

// ===========================================================================
// scan_fill with in-block bsum prefix (kills the separate bsum-scan pass).
// grid = 512 (arr = bid>>8, b = bid&255).  bsum holds RAW per-block sums.
// ===========================================================================
__global__ __launch_bounds__(256) void scan_fill_kernel(
    const int* __restrict__ deg1, const int* __restrict__ deg2,
    const int* __restrict__ bsum, int N,
    int* __restrict__ off1, int* __restrict__ cur1,
    int* __restrict__ off2, int* __restrict__ cur2) {
  int arr = blockIdx.x >> 8;
  int b = blockIdx.x & 255;
  const int* deg = arr ? deg2 : deg1;
  int* off = arr ? off2 : off1;
  int* cur = arr ? cur2 : cur1;
  const int t = threadIdx.x;

  // ---- block prefix over raw bsum segment ----
  __shared__ int redp[4], redt[4];
  int sval = bsum[arr * 256 + t];
  int pv = (t < b) ? sval : 0;  // prefix contribution
  int tv = sval;                // total contribution
#pragma unroll
  for (int m = 1; m < 64; m <<= 1) {
    pv += __shfl_xor(pv, m, 64);
    tv += __shfl_xor(tv, m, 64);
  }
  if ((t & 63) == 0) { redp[t >> 6] = pv; redt[t >> 6] = tv; }
  __syncthreads();
  int prefix = redp[0] + redp[1] + redp[2] + redp[3];
  int total = redt[0] + redt[1] + redt[2] + redt[3];
  if (b == 255 && t == 0) off[N] = total;

  // ---- in-block exclusive scan of deg chunk ----
  int i = b * 256 + t;
  __shared__ int sm[256];
  int v = (i < N) ? deg[i] : 0;
  sm[t] = v;
  __syncthreads();
  for (int d = 1; d < 256; d <<= 1) {
    int val = (t >= d) ? sm[t - d] : 0;
    __syncthreads();
    sm[t] += val;
    __syncthreads();
  }
  int e = sm[t] - v + prefix;
  if (i < N) {
    off[i] = e;
    cur[i] = e;
  }
}

__global__ __launch_bounds__(256) void fill_kernel(
    const int* __restrict__ ei, int E1, const int* __restrict__ ei2, int E2,
    int* __restrict__ cur1, int* __restrict__ cur2,
    int* __restrict__ csr1, int* __restrict__ csr2) {
  int stride = gridDim.x * blockDim.x;
  int Emax = max(E1, E2);
  for (int i = blockIdx.x * blockDim.x + threadIdx.x; i < Emax; i += stride) {
    if (i < E1) {
      int d = ei[E1 + i];
      int p = atomicAdd(&cur1[d], 1);
      csr1[p] = ei[i];
    }
    if (i < E2) {
      int d = ei2[E2 + i];
      int p = atomicAdd(&cur2[d], 1);
      csr2[p] = ei2[i];
    }
  }
}

// ===========================================================================
// Fused gather, fully-masked 4-wide batches (tail included -> max MLP).
//   aggb[n] = sum_{csr1(n)} x[s]
//   tb[n]   = -sum_{csr2(n)} (q'[n].x[s]) x[s]
// ===========================================================================
__global__ __launch_bounds__(256) void gather_fused_kernel(
    const unsigned short* __restrict__ xb, const unsigned short* __restrict__ qb,
    const int* __restrict__ off1, const int* __restrict__ csr1,
    const int* __restrict__ off2, const int* __restrict__ csr2,
    int N, unsigned short* __restrict__ aggb, unsigned short* __restrict__ tb) {
  int wid = blockIdx.x * 4 + (threadIdx.x >> 6);
  if (wid >= N) return;
  int lane = threadIdx.x & 63;

  // --- graph 1: agg (masked 4-wide) ---
  {
    int beg = off1[wid], end = off1[wid + 1];
    float ax = 0.f, ay = 0.f, az = 0.f, aw = 0.f;
    for (int j = beg; j < end; j += 4) {
      int e1 = end - 1;
      int s0 = csr1[j];
      int s1 = csr1[j + 1 < end ? j + 1 : e1];
      int s2 = csr1[j + 2 < end ? j + 2 : e1];
      int s3 = csr1[j + 3 < end ? j + 3 : e1];
      float m1 = (j + 1 < end) ? 1.f : 0.f;
      float m2 = (j + 2 < end) ? 1.f : 0.f;
      float m3 = (j + 3 < end) ? 1.f : 0.f;
      ushort4 r0 = *reinterpret_cast<const ushort4*>(xb + (size_t)s0 * TD + lane * 4);
      ushort4 r1 = *reinterpret_cast<const ushort4*>(xb + (size_t)s1 * TD + lane * 4);
      ushort4 r2 = *reinterpret_cast<const ushort4*>(xb + (size_t)s2 * TD + lane * 4);
      ushort4 r3 = *reinterpret_cast<const ushort4*>(xb + (size_t)s3 * TD + lane * 4);
      ax += bf2f(r0.x) + m1 * bf2f(r1.x) + m2 * bf2f(r2.x) + m3 * bf2f(r3.x);
      ay += bf2f(r0.y) + m1 * bf2f(r1.y) + m2 * bf2f(r2.y) + m3 * bf2f(r3.y);
      az += bf2f(r0.z) + m1 * bf2f(r1.z) + m2 * bf2f(r2.z) + m3 * bf2f(r3.z);
      aw += bf2f(r0.w) + m1 * bf2f(r1.w) + m2 * bf2f(r2.w) + m3 * bf2f(r3.w);
    }
    ushort4 o;
    o.x = f2bf(ax); o.y = f2bf(ay); o.z = f2bf(az); o.w = f2bf(aw);
    *reinterpret_cast<ushort4*>(aggb + (size_t)wid * TD + lane * 4) = o;
  }

  // --- graph 2: t = -sum (q'.x[s]) x[s]  (masked 4-wide, interleaved) ---
  {
    ushort4 qv = *reinterpret_cast<const ushort4*>(qb + (size_t)wid * TD + lane * 4);
    float qx = bf2f(qv.x), qy = bf2f(qv.y), qz = bf2f(qv.z), qw = bf2f(qv.w);
    int beg = off2[wid], end = off2[wid + 1];
    float tx = 0.f, ty = 0.f, tz = 0.f, tw = 0.f;
    for (int j = beg; j < end; j += 4) {
      int e1 = end - 1;
      int s0 = csr2[j];
      int s1 = csr2[j + 1 < end ? j + 1 : e1];
      int s2 = csr2[j + 2 < end ? j + 2 : e1];
      int s3 = csr2[j + 3 < end ? j + 3 : e1];
      ushort4 r0 = *reinterpret_cast<const ushort4*>(xb + (size_t)s0 * TD + lane * 4);
      ushort4 r1 = *reinterpret_cast<const ushort4*>(xb + (size_t)s1 * TD + lane * 4);
      ushort4 r2 = *reinterpret_cast<const ushort4*>(xb + (size_t)s2 * TD + lane * 4);
      ushort4 r3 = *reinterpret_cast<const ushort4*>(xb + (size_t)s3 * TD + lane * 4);
      float a0x = bf2f(r0.x), a0y = bf2f(r0.y), a0z = bf2f(r0.z), a0w = bf2f(r0.w);
      float a1x = bf2f(r1.x), a1y = bf2f(r1.y), a1z = bf2f(r1.z), a1w = bf2f(r1.w);
      float a2x = bf2f(r2.x), a2y = bf2f(r2.y), a2z = bf2f(r2.z), a2w = bf2f(r2.w);
      float a3x = bf2f(r3.x), a3y = bf2f(r3.y), a3z = bf2f(r3.z), a3w = bf2f(r3.w);
      float p0 = qx * a0x + qy * a0y + qz * a0z + qw * a0w;
      float p1 = qx * a1x + qy * a1y + qz * a1z + qw * a1w;
      float p2 = qx * a2x + qy * a2y + qz * a2z + qw * a2w;
      float p3 = qx * a3x + qy * a3y + qz * a3z + qw * a3w;
#pragma unroll
      for (int m = 1; m < 64; m <<= 1) {
        p0 += __shfl_xor(p0, m, 64);
        p1 += __shfl_xor(p1, m, 64);
        p2 += __shfl_xor(p2, m, 64);
        p3 += __shfl_xor(p3, m, 64);
      }
      p1 = (j + 1 < end) ? p1 : 0.f;
      p2 = (j + 2 < end) ? p2 : 0.f;
      p3 = (j + 3 < end) ? p3 : 0.f;
      tx -= p0 * a0x + p1 * a1x + p2 * a2x + p3 * a3x;
      ty -= p0 * a0y + p1 * a1y + p2 * a2y + p3 * a3y;
      tz -= p0 * a0z + p1 * a1z + p2 * a2z + p3 * a3z;
      tw -= p0 * a0w + p1 * a1w + p2 * a2w + p3 * a3w;
    }
    ushort4 o;
    o.x = f2bf(tx); o.y = f2bf(ty); o.z = f2bf(tz); o.w = f2bf(tw);
    *reinterpret_cast<ushort4*>(tb + (size_t)wid * TD + lane * 4) = o;
  }
}

// ===========================================================================
// LDS-staged MFMA GEMM, tile 128x256, 512 thr = 8 waves (2x4 of 64x64).
//   MODE 0: q' = xb @ Gt                    (K=256, bf16 out -> qb)
//   MODE 1: out = xb@W0 + aggb@W1 + tb@Wv   (K=768 segmented, fp32 out)
// KSTEP=64, 16x16x32 bf16 MFMA, global_load_lds(16B) + XOR-(row&7) swizzle.
// ===========================================================================
template <int MODE>
__global__ __launch_bounds__(512) void gemm_lds(
    const unsigned short* __restrict__ xb, const unsigned short* __restrict__ aggb,
    const unsigned short* __restrict__ tb, const unsigned short* __restrict__ wt,
    const unsigned short* __restrict__ gt, float* __restrict__ out,
    unsigned short* __restrict__ qb, int M) {
  __shared__ __align__(16) unsigned short sA[128 * 64];
  __shared__ __align__(16) unsigned short sB[256 * 64];

  const int m0 = blockIdx.x * 128;
  const int tid = threadIdx.x;
  const int w = tid >> 6, l = tid & 63;
  const int lrow = l >> 3, lslot = l & 7;
  const int wr = w >> 2, wc = w & 3;  // 2x4 wave grid, 64x64 each

  f32x4 acc[4][4] = {};

  const int KTOT = (MODE == 0) ? 256 : 768;

  for (int k0 = 0; k0 < KTOT; k0 += 64) {
    const unsigned short* Ap;
    const unsigned short* Bp;
    int ks;
    if (MODE == 0) {
      Ap = xb; Bp = gt; ks = k0;
    } else {
      int seg = k0 >> 8;  // 0: x@W0, 1: agg@W1, 2: t@Wv
      Ap = seg == 0 ? xb : seg == 1 ? aggb : tb;
      Bp = wt + seg * 65536;
      ks = k0 & 255;
    }

    // ---- stage A tile [128][64]: wave w stages rows w*16 .. w*16+15 ----
#pragma unroll
    for (int i = 0; i < 2; i++) {
      int row = w * 16 + i * 8 + lrow;
      int gr = m0 + row;
      if (gr >= M) gr = M - 1;
      int g = lslot ^ lrow;
      const unsigned short* src = Ap + (size_t)gr * TD + ks + g * 8;
      unsigned short* dst = sA + (w * 16 + i * 8) * 64;
      __builtin_amdgcn_global_load_lds(
          (const __attribute__((address_space(1))) void*)src,
          (__attribute__((address_space(3))) void*)dst, 16, 0, 0);
    }
    // ---- stage B tile [256][64]: wave w stages rows w*32 .. w*32+31 ----
#pragma unroll
    for (int i = 0; i < 4; i++) {
      int row = w * 32 + i * 8 + lrow;
      int g = lslot ^ lrow;
      const unsigned short* src = Bp + (size_t)row * TD + ks + g * 8;
      unsigned short* dst = sB + (w * 32 + i * 8) * 64;
      __builtin_amdgcn_global_load_lds(
          (const __attribute__((address_space(1))) void*)src,
          (__attribute__((address_space(3))) void*)dst, 16, 0, 0);
    }
    __syncthreads();

#pragma unroll
    for (int kk = 0; kk < 2; kk++) {
      short8 a[4], b[4];
#pragma unroll
      for (int m = 0; m < 4; m++) {
        int row = wr * 64 + m * 16 + (l & 15);
        int slot = (kk * 4 + (l >> 4)) ^ (row & 7);
        a[m] = *reinterpret_cast<const short8*>(&sA[row * 64 + slot * 8]);
      }
#pragma unroll
      for (int n = 0; n < 4; n++) {
        int row = wc * 64 + n * 16 + (l & 15);
        int slot = (kk * 4 + (l >> 4)) ^ (row & 7);
        b[n] = *reinterpret_cast<const short8*>(&sB[row * 64 + slot * 8]);
      }
#pragma unroll
      for (int m = 0; m < 4; m++)
#pragma unroll
        for (int n = 0; n < 4; n++)
          acc[m][n] =
              __builtin_amdgcn_mfma_f32_16x16x32_bf16(a[m], b[n], acc[m][n], 0, 0, 0);
    }
    __syncthreads();
  }

  // ---- store ----
  if (MODE == 1) {
#pragma unroll
    for (int m = 0; m < 4; m++)
#pragma unroll
      for (int n = 0; n < 4; n++)
#pragma unroll
        for (int j = 0; j < 4; j++) {
          int r = m0 + wr * 64 + m * 16 + (l >> 4) * 4 + j;
          if (r < M)
            out[(size_t)r * TD + wc * 64 + n * 16 + (l & 15)] = acc[m][n][j];
        }
  } else {
#pragma unroll
    for (int m = 0; m < 4; m++)
#pragma unroll
      for (int n = 0; n < 4; n++)
#pragma unroll
        for (int j = 0; j < 4; j++) {
          int r = m0 + wr * 64 + m * 16 + (l >> 4) * 4 + j;
          if (r < M)
            qb[(size_t)r * TD + wc * 64 + n * 16 + (l & 15)] =
                f2bf(acc[m][n][j]);
        }
  }
}

// ===========================================================================
extern "C" void kernel_launch(void* const* d_in, const int* in_sizes, int n_in,
                              void* d_out, int out_size, void* d_ws,
                              size_t ws_size, hipStream_t stream) {
  const float* x  = (const float*)d_in[0];
  const int*   ei  = (const int*)d_in[1];
  const int*   ei2 = (const int*)d_in[2];
  const float* W0 = (const float*)d_in[3];
  const float* W1 = (const float*)d_in[4];
  const float* Wq = (const float*)d_in[5];
  const float* Wk = (const float*)d_in[6];
  const float* Wv = (const float*)d_in[7];

  const int N  = in_sizes[0] / TD;
  const int E1 = in_sizes[1] / 2;
  const int E2 = in_sizes[2] / 2;

  float* out = (float*)d_out;
  const size_t rowN = (size_t)N * TD;

  // ---- workspace layout ----
  char* p = (char*)d_ws;
  unsigned short* xb   = (unsigned short*)p; p += rowN * 2;
  unsigned short* aggb = (unsigned short*)p; p += rowN * 2;
  unsigned short* qb   = (unsigned short*)p; p += rowN * 2;
  unsigned short* tb   = (unsigned short*)p; p += rowN * 2;
  unsigned short* wt   = (unsigned short*)p; p += 3 * 65536 * 2;  // W0t,W1t,Wvt
  unsigned short* gt   = (unsigned short*)p; p += 65536 * 2;
  unsigned short* wqb  = (unsigned short*)p; p += 65536 * 2;
  unsigned short* wkb  = (unsigned short*)p; p += 65536 * 2;
  int* off1 = (int*)p; p += (N + 1) * 4;
  int* cur1 = (int*)p; p += N * 4;
  int* off2 = (int*)p; p += (N + 1) * 4;
  int* cur2 = (int*)p; p += N * 4;
  int* csr1 = (int*)p; p += (size_t)E1 * 4;
  int* csr2 = (int*)p; p += (size_t)E2 * 4;
  int* deg1 = (int*)p; p += N * 4;
  int* deg2 = (int*)p; p += N * 4;
  int* bsum = (int*)p; p += 512 * 4;

  // 1. zero degree arrays
  hipMemsetAsync(deg1, 0, (size_t)2 * N * sizeof(int), stream);

  // 2. prologue: hist + all dtype conversions in one dispatch
  long total8 = rowN / 8;
  int nbH = 512;
  int nbX = (int)((total8 + 255) / 256);
  prologue_kernel<<<nbH + nbX + 64 + 768, 256, 0, stream>>>(
      ei, E1, ei2, E2, deg1, deg2, x, xb, total8, Wq, Wk, wqb, wkb, W0, W1, Wv,
      wt, nbH, nbX);

  // 3. scan phase A + G = Wq@Wk^T, then fused prefix+fill of off/cur
  scanA_gemmG_kernel<<<516, 256, 0, stream>>>(deg1, deg2, N, bsum, wqb, wkb, gt);
  scan_fill_kernel<<<512, 256, 0, stream>>>(deg1, deg2, bsum, N, off1, cur1,
                                            off2, cur2);
  fill_kernel<<<1024, 256, 0, stream>>>(ei, E1, ei2, E2, cur1, cur2, csr1, csr2);

  // 4. q' = x @ G
  int gblk = (N + 127) / 128;
  gemm_lds<0><<<gblk, 512, 0, stream>>>(xb, aggb, tb, wt, gt, out, qb, N);

  // 5. fused gather: aggb (graph1) + tb (graph2, needs q')
  gather_fused_kernel<<<(N + 3) / 4, 256, 0, stream>>>(xb, qb, off1, csr1,
                                                       off2, csr2, N, aggb, tb);

  // 6. out = x@W0 + agg@W1 + t@Wv   (t already negated)
  gemm_lds<1><<<gblk, 512, 0, stream>>>(xb, aggb, tb, wt, gt, out, qb, N);
}